// Round 8
// baseline (591.915 us; speedup 1.0000x reference)
//
#include <hip/hip_runtime.h>
#include <hip/hip_bf16.h>
#include <math.h>

typedef __bf16 bf16_t;
typedef __bf16 bf16x2 __attribute__((ext_vector_type(2)));
typedef __bf16 bf16x4 __attribute__((ext_vector_type(4)));
typedef __bf16 bf16x8 __attribute__((ext_vector_type(8)));
typedef float f32x4 __attribute__((ext_vector_type(4)));
typedef float f32x16 __attribute__((ext_vector_type(16)));

#define LOG2E 1.44269504088896340736f

// async global->LDS DMA, 16B per lane; LDS dest = wave-uniform base + lane*16
#define GL2LDS(g, l)                                                     \
  __builtin_amdgcn_global_load_lds(                                      \
      (const __attribute__((address_space(1))) unsigned int*)(g),        \
      (__attribute__((address_space(3))) unsigned int*)(l), 16, 0, 0)

// raw barrier with compiler memory fence (NO implicit vmcnt drain)
#define BAR() asm volatile("s_barrier" ::: "memory")
#define VMCNT(n) asm volatile("s_waitcnt vmcnt(" #n ")" ::: "memory")
#define LGKM0()                                         \
  do {                                                  \
    asm volatile("s_waitcnt lgkmcnt(0)" ::: "memory");  \
    __builtin_amdgcn_sched_barrier(0);                  \
  } while (0)

static __device__ __forceinline__ unsigned pk2(bf16_t a, bf16_t b) {
  bf16x2 t;
  t[0] = a;
  t[1] = b;
  return __builtin_bit_cast(unsigned, t);
}

// ------------- convert f32 -> bf16, 8 elems/thread ------------------------
__global__ __launch_bounds__(256) void convert_f32_bf16(const float* __restrict__ in,
                                                        bf16_t* __restrict__ out) {
  const size_t idx = (size_t)(blockIdx.x * 256 + threadIdx.x) * 8;
  f32x4 a = *(const f32x4*)&in[idx];
  f32x4 b = *(const f32x4*)&in[idx + 4];
  bf16x8 v;
#pragma unroll
  for (int i = 0; i < 4; i++) { v[i] = (bf16_t)a[i]; v[i + 4] = (bf16_t)b[i]; }
  *(bf16x8*)&out[idx] = v;
}

// ------------- transpose+convert: in f32 [R][C] -> out bf16 [C][R] --------
__global__ __launch_bounds__(256) void transpose_f32_bf16(const float* __restrict__ in,
                                                          bf16_t* __restrict__ out,
                                                          int R, int C) {
  __shared__ bf16_t t[64][65];
  const int c0 = blockIdx.x * 64, r0 = blockIdx.y * 64;
  const int tx = threadIdx.x, ty = threadIdx.y;  // 64 x 4
#pragma unroll
  for (int i = 0; i < 16; i++) {
    int r = ty + i * 4;
    t[r][tx] = (bf16_t)in[(size_t)(r0 + r) * C + c0 + tx];
  }
  __syncthreads();
#pragma unroll
  for (int i = 0; i < 16; i++) {
    int r = ty + i * 4;
    out[(size_t)(c0 + r) * R + r0 + tx] = t[tx][r];
  }
}

// ---- 128x128 GEMM v5: B-only LDS (4-buf, prefetch-2), A direct-to-reg ----
// Round-7 post-mortem: per-CU K-step time ~1190cy ~= LDS port time for the
// 48KB/step (16KB DMA wr + 32KB frag rd) x3 blocks -> LDS-BW bound, not
// schedule-bound. Fix: A-fragments are per-lane contiguous 16B global reads
// (L2-resident, ~2MB/XCD panel w/ XCD swizzle) -> load A global->reg one
// step ahead (double frag set, statically indexed via unroll-4); only B
// goes DMA->LDS (4 bufs x 8KB = 32KB, prefetch distance 2). LDS traffic
// per block-step 48->24KB. Issue order A(t+1) then B(t+2) makes VMCNT(2)
// retire exactly B(t+1)+A(t+1), leaving B(t+2) in flight (T4).
// B swizzle (verified zero-conflict): LDS chunk (r,p) holds global chunk
// p ^ ((r>>1)&3); frag read at chunk lq ^ ((row>>1)&3) -> free 2-way.
// MODE 0: epilogue scatters qkv into Q(pre-scaled)/K [B][H][N][64], Vt [B][H][64][N]
// MODE 1: epilogue adds f32 bias, writes f32 [M][1024]
template <int MODE>
__global__ __launch_bounds__(256, 4) void gemmT(const bf16_t* __restrict__ A,
                                                const bf16_t* __restrict__ Bt,
                                                bf16_t* __restrict__ Qb,
                                                bf16_t* __restrict__ Kb,
                                                bf16_t* __restrict__ Vtb,
                                                const float* __restrict__ bias,
                                                float* __restrict__ Out) {
  constexpr int K = 1024;
  constexpr int NT = K / 32;  // 32 K-tiles
  __shared__ __align__(16) bf16_t Bs[4][128 * 32];
  // XCD-aware bijective swizzle (grid sizes are multiples of 8)
  const int gx = gridDim.x;
  const int lin = blockIdx.y * gx + blockIdx.x;
  const int per = (gx * gridDim.y) >> 3;
  const int swz = (lin & 7) * per + (lin >> 3);
  const int m0 = (swz / gx) * 128, n0 = (swz % gx) * 128;
  const int tid = threadIdx.x;
  const int w = tid >> 6, l = tid & 63;
  const int lr = l & 15, lq = l >> 4;
  const int wm = w >> 1, wn = w & 1;  // 2 x 2 wave grid, wave tile 64x64

  // B staging: chunk c = slot*256 + tid; r = c>>2, LDS pos p = c&3,
  // source chunk = p ^ ((r>>1)&3) (slot-invariant)
  const int rs = tid >> 2, ps = tid & 3;
  const int cs = (ps ^ ((rs >> 1) & 3)) * 8;
  const size_t gB0 = (size_t)(n0 + rs) * K + cs;
  const size_t gB1 = (size_t)(n0 + 64 + rs) * K + cs;
  const int ldsu0 = (w * 64) * 8;          // wave-uniform LDS elem offsets
  const int ldsu1 = (256 + w * 64) * 8;

#define STGB(bf_, kt_)                                  \
  do {                                                  \
    const size_t kk_ = (size_t)(kt_) * 32;              \
    GL2LDS(&Bt[gB0 + kk_], &Bs[bf_][ldsu0]);            \
    GL2LDS(&Bt[gB1 + kk_], &Bs[bf_][ldsu1]);            \
  } while (0)

  // A direct: per-lane contiguous 16B at row (m0+wm*64+mf*16+lr), col k0+lq*8
  const bf16_t* Ab = &A[(size_t)(m0 + wm * 64 + lr) * K + lq * 8];
#define LDA(dst_, kt_)                                            \
  do {                                                            \
    _Pragma("unroll") for (int mf_ = 0; mf_ < 4; mf_++)           \
        (dst_)[mf_] = *(const bf16x8*)&Ab[(size_t)mf_ * 16 * K + (kt_) * 32]; \
  } while (0)

  // B frag ds_read offsets (elems); row*64B base + swizzled 16B chunk
  int boff[4];
#pragma unroll
  for (int nf = 0; nf < 4; nf++) {
    const int row = wn * 64 + nf * 16 + lr;
    boff[nf] = row * 32 + ((lq ^ ((row >> 1) & 3)) << 3);
  }

  f32x4 acc[4][4] = {};
  bf16x8 afr[2][4];

  // prologue: B(0)->buf0, A(0)->afr[0], B(1)->buf1; VMCNT(2) keeps B(1)
  STGB(0, 0);
  LDA(afr[0], 0);
  STGB(1, 1);
  VMCNT(2);
  BAR();

  for (int tb = 0; tb < NT; tb += 4) {
#pragma unroll
    for (int s = 0; s < 4; s++) {
      const int t = tb + s;
      // 1) A prefetch for t+1 (issue FIRST so VMCNT(2) can retire it)
      if (t + 1 < NT) LDA(afr[(s + 1) & 1], t + 1);
      // 2) B DMA for t+2
      if (t + 2 < NT) STGB((s + 2) & 3, t + 2);
      // 3) B frags from LDS buf s
      bf16x8 bv[4];
#pragma unroll
      for (int nf = 0; nf < 4; nf++)
        bv[nf] = *(const bf16x8*)&Bs[s][boff[nf]];
      LGKM0();
      __builtin_amdgcn_s_setprio(1);
#pragma unroll
      for (int mf = 0; mf < 4; mf++)
#pragma unroll
        for (int nf = 0; nf < 4; nf++)
          acc[mf][nf] = __builtin_amdgcn_mfma_f32_16x16x32_bf16(
              afr[s & 1][mf], bv[nf], acc[mf][nf], 0, 0, 0);
      __builtin_amdgcn_s_setprio(0);
      // counted wait: retire B(t+1)+A(t+1); keep B(t+2) in flight
      if (t < NT - 2) { VMCNT(2); } else if (t == NT - 2) { VMCNT(0); }
      BAR();
    }
  }

#pragma unroll
  for (int mf = 0; mf < 4; mf++)
#pragma unroll
    for (int nf = 0; nf < 4; nf++)
#pragma unroll
      for (int i = 0; i < 4; i++) {
        const int m = m0 + wm * 64 + mf * 16 + lq * 4 + i;  // C/D row=(lane>>4)*4+i
        const int c = n0 + wn * 64 + nf * 16 + lr;          //     col=lane&15
        const float v = acc[mf][nf][i];
        if (MODE == 1) {
          Out[(size_t)m * 1024 + c] = v + bias[c];
        } else {
          const int b = m >> 10, n = m & 1023;
          const int which = c >> 10, cc = c & 1023;
          const int hh = cc >> 6, d = cc & 63;
          const size_t qk = ((size_t)((b * 16 + hh) * 1024 + n)) * 64 + d;
          if (which == 0)
            Qb[qk] = (bf16_t)(v * (0.125f * LOG2E));  // fold softmax scale+log2e
          else if (which == 1)
            Kb[qk] = (bf16_t)v;
          else
            Vtb[((size_t)((b * 16 + hh) * 64 + d)) * 1024 + n] = (bf16_t)v;
        }
      }
}

// ------------- flash attention v6: 32x32 MFMA, fully in-register P --------
// (unchanged from round 7 — correctness proven; kept for clean ablation)
__global__ __launch_bounds__(256) void attn128(const bf16_t* __restrict__ Qb,
                                               const bf16_t* __restrict__ Kb,
                                               const bf16_t* __restrict__ Vtb,
                                               bf16_t* __restrict__ Ob) {
  __shared__ __align__(16) bf16_t Ks[2][64 * 64];
  __shared__ __align__(16) bf16_t Vs[2][64 * 64];
  const int bid = blockIdx.x;
  const int qt = bid >> 7, b = (bid >> 4) & 7, h = bid & 15;
  const bf16_t* Qh = Qb + (size_t)((b * 16 + h) * 1024) * 64;
  const bf16_t* Kh = Kb + (size_t)((b * 16 + h) * 1024) * 64;
  const bf16_t* Vh = Vtb + (size_t)((b * 16 + h) * 64) * 1024;  // [64][1024] = V^T
  const int tid = threadIdx.x, w = tid >> 6, l = tid & 63;
  const int lq31 = l & 31, hi = l >> 5;
  const int q0w = qt * 128 + w * 32;
  const int ksw = lq31 & 7;

  // staging: chunk c = slot*256 + tid; r = c>>3, pos p = tid&7,
  // source chunk = p ^ (r&7)  ((r+32)&7 == r&7 -> slot-invariant)
  const int r0 = tid >> 3, p0 = tid & 7;
  const int ck = (p0 ^ (r0 & 7)) * 8;
  const int ldsS0 = (w * 64) * 8;
  const int ldsS1 = (256 + w * 64) * 8;

#define STGKV(bf_, j_)                                                  \
  do {                                                                  \
    const size_t jb = (size_t)(j_) * 64;                                \
    GL2LDS(&Kh[(jb + r0) * 64 + ck], &Ks[bf_][ldsS0]);                  \
    GL2LDS(&Kh[(jb + r0 + 32) * 64 + ck], &Ks[bf_][ldsS1]);             \
    GL2LDS(&Vh[(size_t)r0 * 1024 + jb + ck], &Vs[bf_][ldsS0]);          \
    GL2LDS(&Vh[(size_t)(r0 + 32) * 1024 + jb + ck], &Vs[bf_][ldsS1]);   \
  } while (0)

  // Q B-frags: B[k=c*16+hi*8+j][n=q=lane&31] = Q[q0w+lq31][c*16+hi*8+j]
  bf16x8 qf[4];
#pragma unroll
  for (int c = 0; c < 4; c++)
    qf[c] = *(const bf16x8*)&Qh[(size_t)(q0w + lq31) * 64 + c * 16 + hi * 8];

  STGKV(0, 0);
  VMCNT(0);
  BAR();

  f32x16 o0 = {}, o1 = {};  // O^T: rows d = db*32 + (reg&3)+8*(reg>>2)+4*hi, col q
  float denom = 0.0f;

  for (int it = 0; it < 16; ++it) {
    const int buf = it & 1;
    if (it < 15) STGKV(buf ^ 1, it + 1);
    // QK^T swapped: s[kb] covers kv rows kb*32..+31, q cols = lane&31
    f32x16 s0 = {}, s1 = {};
    __builtin_amdgcn_s_setprio(1);
#pragma unroll
    for (int c = 0; c < 4; c++) {
      const int col = ((c * 2 + hi) ^ ksw) << 3;
      bf16x8 kf0 = *(const bf16x8*)&Ks[buf][lq31 * 64 + col];
      bf16x8 kf1 = *(const bf16x8*)&Ks[buf][(32 + lq31) * 64 + col];
      s0 = __builtin_amdgcn_mfma_f32_32x32x16_bf16(kf0, qf[c], s0, 0, 0, 0);
      s1 = __builtin_amdgcn_mfma_f32_32x32x16_bf16(kf1, qf[c], s1, 0, 0, 0);
    }
    __builtin_amdgcn_s_setprio(0);
    // exp2 -> bf16 pairs; rowsum of ROUNDED p (matches numerator numerics)
    unsigned wds[16];
    float dl = 0.0f;
#pragma unroll
    for (int j = 0; j < 8; j++) {
      bf16_t e0 = (bf16_t)exp2f(s0[2 * j]), e1 = (bf16_t)exp2f(s0[2 * j + 1]);
      dl += (float)e0 + (float)e1;
      wds[j] = pk2(e0, e1);
    }
#pragma unroll
    for (int j = 0; j < 8; j++) {
      bf16_t e0 = (bf16_t)exp2f(s1[2 * j]), e1 = (bf16_t)exp2f(s1[2 * j + 1]);
      dl += (float)e0 + (float)e1;
      wds[8 + j] = pk2(e0, e1);
    }
    denom += dl + __shfl_xor(dl, 32);
    // build PV B-frags: frag ck needs rows ck*16 + hi*8 + (0..7)
    bf16x8 pf[4];
#pragma unroll
    for (int q2 = 0; q2 < 4; q2++) {
      const int base = (q2 >> 1) * 8 + (q2 & 1) * 4;
      const unsigned a0 = wds[base], a1 = wds[base + 1];
      const unsigned a2 = wds[base + 2], a3 = wds[base + 3];
      const unsigned x0 = __shfl_xor(a0, 32), x1 = __shfl_xor(a1, 32);
      const unsigned x2 = __shfl_xor(a2, 32), x3 = __shfl_xor(a3, 32);
      union { unsigned u[4]; bf16x8 v; } u;
      u.u[0] = hi ? x2 : a0;
      u.u[1] = hi ? x3 : a1;
      u.u[2] = hi ? a2 : x0;
      u.u[3] = hi ? a3 : x1;
      pf[q2] = u.v;
    }
    // PV swapped: o[db] += mfma(V^T-frag, P-frag)
    __builtin_amdgcn_s_setprio(1);
#pragma unroll
    for (int c = 0; c < 4; c++) {
      const int col = ((c * 2 + hi) ^ ksw) << 3;
      bf16x8 vf0 = *(const bf16x8*)&Vs[buf][lq31 * 64 + col];
      bf16x8 vf1 = *(const bf16x8*)&Vs[buf][(32 + lq31) * 64 + col];
      o0 = __builtin_amdgcn_mfma_f32_32x32x16_bf16(vf0, pf[c], o0, 0, 0, 0);
      o1 = __builtin_amdgcn_mfma_f32_32x32x16_bf16(vf1, pf[c], o1, 0, 0, 0);
    }
    __builtin_amdgcn_s_setprio(0);
    VMCNT(0);
    BAR();
  }
  // epilogue: O[q][d], d = db*32 + rg*8 + hi*4 + i, q = lane&31 (lane-local inv)
  const float inv = 1.0f / denom;
  const int grow = b * 1024 + q0w + lq31;
#pragma unroll
  for (int db = 0; db < 2; db++)
#pragma unroll
    for (int rg = 0; rg < 4; rg++) {
      bf16x4 ov;
#pragma unroll
      for (int i = 0; i < 4; i++)
        ov[i] = (bf16_t)((db ? o1[rg * 4 + i] : o0[rg * 4 + i]) * inv);
      *(bf16x4*)&Ob[(size_t)grow * 1024 + h * 64 + db * 32 + rg * 8 + hi * 4] = ov;
    }
}

extern "C" void kernel_launch(void* const* d_in, const int* in_sizes, int n_in,
                              void* d_out, int out_size, void* d_ws, size_t ws_size,
                              hipStream_t stream) {
  const float* x     = (const float*)d_in[0];  // [8,1024,1024] f32
  const float* w_qkv = (const float*)d_in[1];  // [1024,3072] f32
  const float* w_out = (const float*)d_in[2];  // [1024,1024] f32
  const float* b_out = (const float*)d_in[3];  // [1024] f32
  float* out = (float*)d_out;                  // [8,1024,1024] f32

  bf16_t* ws = (bf16_t*)d_ws;
  const size_t SZ = (size_t)8 * 1024 * 1024;  // elems per 16MB buffer
  bf16_t* Qb  = ws;            // [B][H][N][64]  (pre-scaled)
  bf16_t* Kb  = Qb + SZ;       // [B][H][N][64]
  bf16_t* Vtb = Kb + SZ;       // [B][H][64][N]
  bf16_t* Ob  = Vtb + SZ;      // [B*N][H*64]; also aliases Xb (dead after gemm0)
  bf16_t* Wqt = Ob + SZ;       // [3072][1024]
  bf16_t* Wot = Wqt + (size_t)3072 * 1024;  // [1024][1024]
  bf16_t* Xb  = Ob;            // x as bf16 [8192][1024]
  // total ws use: 72 MB

  hipLaunchKernelGGL(convert_f32_bf16, dim3(4096), dim3(256), 0, stream, x, Xb);
  hipLaunchKernelGGL(transpose_f32_bf16, dim3(48, 16), dim3(64, 4), 0, stream,
                     w_qkv, Wqt, 1024, 3072);
  hipLaunchKernelGGL(transpose_f32_bf16, dim3(16, 16), dim3(64, 4), 0, stream,
                     w_out, Wot, 1024, 1024);
  hipLaunchKernelGGL((gemmT<0>), dim3(24, 64), dim3(256), 0, stream,
                     Xb, Wqt, Qb, Kb, Vtb, (const float*)nullptr, (float*)nullptr);
  hipLaunchKernelGGL(attn128, dim3(1024), dim3(256), 0, stream, Qb, Kb, Vtb, Ob);
  hipLaunchKernelGGL((gemmT<1>), dim3(8, 64), dim3(256), 0, stream,
                     Ob, Wot, (bf16_t*)nullptr, (bf16_t*)nullptr, (bf16_t*)nullptr,
                     b_out, out);
}

// Round 9
// 282.180 us; speedup vs baseline: 2.0977x; 2.0977x over previous
//
#include <hip/hip_runtime.h>
#include <hip/hip_bf16.h>
#include <math.h>

typedef __bf16 bf16_t;
typedef __bf16 bf16x2 __attribute__((ext_vector_type(2)));
typedef __bf16 bf16x4 __attribute__((ext_vector_type(4)));
typedef __bf16 bf16x8 __attribute__((ext_vector_type(8)));
typedef float f32x4 __attribute__((ext_vector_type(4)));
typedef float f32x16 __attribute__((ext_vector_type(16)));

#define LOG2E 1.44269504088896340736f

// async global->LDS DMA, 16B per lane; LDS dest = wave-uniform base + lane*16
#define GL2LDS(g, l)                                                     \
  __builtin_amdgcn_global_load_lds(                                      \
      (const __attribute__((address_space(1))) unsigned int*)(g),        \
      (__attribute__((address_space(3))) unsigned int*)(l), 16, 0, 0)

// raw barrier with compiler memory fence (NO implicit vmcnt drain)
#define BAR() asm volatile("s_barrier" ::: "memory")
#define VMCNT(n) asm volatile("s_waitcnt vmcnt(" #n ")" ::: "memory")
#define LGKM0()                                         \
  do {                                                  \
    asm volatile("s_waitcnt lgkmcnt(0)" ::: "memory");  \
    __builtin_amdgcn_sched_barrier(0);                  \
  } while (0)

static __device__ __forceinline__ unsigned pk2(bf16_t a, bf16_t b) {
  bf16x2 t;
  t[0] = a;
  t[1] = b;
  return __builtin_bit_cast(unsigned, t);
}

// ------------- convert f32 -> bf16, 8 elems/thread ------------------------
__global__ __launch_bounds__(256) void convert_f32_bf16(const float* __restrict__ in,
                                                        bf16_t* __restrict__ out) {
  const size_t idx = (size_t)(blockIdx.x * 256 + threadIdx.x) * 8;
  f32x4 a = *(const f32x4*)&in[idx];
  f32x4 b = *(const f32x4*)&in[idx + 4];
  bf16x8 v;
#pragma unroll
  for (int i = 0; i < 4; i++) { v[i] = (bf16_t)a[i]; v[i + 4] = (bf16_t)b[i]; }
  *(bf16x8*)&out[idx] = v;
}

// ------------- transpose+convert: in f32 [R][C] -> out bf16 [C][R] --------
__global__ __launch_bounds__(256) void transpose_f32_bf16(const float* __restrict__ in,
                                                          bf16_t* __restrict__ out,
                                                          int R, int C) {
  __shared__ bf16_t t[64][65];
  const int c0 = blockIdx.x * 64, r0 = blockIdx.y * 64;
  const int tx = threadIdx.x, ty = threadIdx.y;  // 64 x 4
#pragma unroll
  for (int i = 0; i < 16; i++) {
    int r = ty + i * 4;
    t[r][tx] = (bf16_t)in[(size_t)(r0 + r) * C + c0 + tx];
  }
  __syncthreads();
#pragma unroll
  for (int i = 0; i < 16; i++) {
    int r = ty + i * 4;
    out[(size_t)(c0 + r) * R + r0 + tx] = t[tx][r];
  }
}

// ---- 128xBN MFMA GEMM, BK=32, TRIPLE-buffered, counted vmcnt -------------
// EXACT round-4 structure (95us gemm0, VGPR 76, FETCH 57.6MB, 0 conflicts)
// with the B-tile width templated: NW = n-frags per wave. NW=4 -> BN=128
// (gemm0, round-4 config, grid 24x64 = 6 blocks/CU). NW=2 -> BN=64 (gemm1,
// grid 16x64 = 1024 blocks = 4/CU; round-4/6 showed gemm1 at BN=128 was
// grid-limited to 2 blocks/CU and ran ~95us for 1/3 the FLOPs).
// Round-8 lesson: launch_bounds(256,4) caps 128 VGPR; adding 32 VGPRs of
// A-frags spilled acc to scratch (WRITE_SIZE 50->828MB, 3.7x dur). This
// version stays at VGPR<=76 (NW=4) / ~60 (NW=2).
// Prefetch distance 2: at tile t stage tile t+2 into buf[(t+2)%3]; the
// end-of-tile counted VMCNT retires group t+1 (issued one full tile ago)
// and leaves group t+2 in flight (T4). Group = 2+NW/2 loads.
// Swizzle (verified zero-conflict): LDS chunk (r,p) holds global chunk
// p ^ ((r>>1)&3); frag read at chunk lq ^ ((row>>1)&3) -> free 2-way.
// MODE 0: epilogue scatters qkv into Q(pre-scaled)/K [B][H][N][64], Vt [B][H][64][N]
// MODE 1: epilogue adds f32 bias, writes f32 [M][1024]
template <int MODE, int NW>
__global__ __launch_bounds__(256, 4) void gemmT(const bf16_t* __restrict__ A,
                                                const bf16_t* __restrict__ Bt,
                                                bf16_t* __restrict__ Qb,
                                                bf16_t* __restrict__ Kb,
                                                bf16_t* __restrict__ Vtb,
                                                const float* __restrict__ bias,
                                                float* __restrict__ Out) {
  constexpr int K = 1024;
  constexpr int NT = K / 32;       // 32 K-tiles
  constexpr int BN = NW * 32;      // block N-tile (2 waves in n)
  __shared__ __align__(16) bf16_t As[3][128 * 32];
  __shared__ __align__(16) bf16_t Bs[3][BN * 32];
  // XCD-aware bijective swizzle (grid sizes are multiples of 8)
  const int gx = gridDim.x;
  const int lin = blockIdx.y * gx + blockIdx.x;
  const int per = (gx * gridDim.y) >> 3;
  const int swz = (lin & 7) * per + (lin >> 3);
  const int m0 = (swz / gx) * 128, n0 = (swz % gx) * BN;
  const int tid = threadIdx.x;
  const int w = tid >> 6, l = tid & 63;
  const int lr = l & 15, lq = l >> 4;
  const int wm = w >> 1, wn = w & 1;  // 2 x 2 wave grid, wave tile 64 x (NW*16)

  // staging: chunk c = slot*256 + tid; r = c>>2 = slot*64 + (tid>>2),
  // LDS pos p = c&3, source chunk = p ^ ((r>>1)&3) (slot-invariant)
  const int rs = tid >> 2, ps = tid & 3;
  const int cs = (ps ^ ((rs >> 1) & 3)) * 8;
  const size_t gA0 = (size_t)(m0 + rs) * K + cs;
  const size_t gA1 = (size_t)(m0 + 64 + rs) * K + cs;
  const size_t gB0 = (size_t)(n0 + rs) * K + cs;
  const size_t gB1 = (size_t)(n0 + 64 + rs) * K + cs;  // used only if NW==4
  const int ldsu0 = (w * 64) * 8;          // wave-uniform LDS elem offsets
  const int ldsu1 = (256 + w * 64) * 8;

#define STG(bf_, kt_)                                          \
  do {                                                         \
    const size_t kk_ = (size_t)(kt_) * 32;                     \
    GL2LDS(&A[gA0 + kk_], &As[bf_][ldsu0]);                    \
    GL2LDS(&A[gA1 + kk_], &As[bf_][ldsu1]);                    \
    GL2LDS(&Bt[gB0 + kk_], &Bs[bf_][ldsu0]);                   \
    if constexpr (NW == 4) GL2LDS(&Bt[gB1 + kk_], &Bs[bf_][ldsu1]); \
  } while (0)

  // frag ds_read offsets (elems); row*64B base + swizzled 16B chunk
  int aoff[4], boff[NW];
#pragma unroll
  for (int mf = 0; mf < 4; mf++) {
    const int row = wm * 64 + mf * 16 + lr;
    aoff[mf] = row * 32 + ((lq ^ ((row >> 1) & 3)) << 3);
  }
#pragma unroll
  for (int nf = 0; nf < NW; nf++) {
    const int row = wn * (NW * 16) + nf * 16 + lr;
    boff[nf] = row * 32 + ((lq ^ ((row >> 1) & 3)) << 3);
  }

  f32x4 acc[4][NW] = {};

  // prologue: stage tiles 0 and 1; counted wait retires group 0 only
  STG(0, 0);
  STG(1, 1);
  if constexpr (NW == 4) { VMCNT(4); } else { VMCNT(3); }
  BAR();

  for (int t = 0; t < NT; ++t) {
    const int bufR = t % 3;
    if (t + 2 < NT) STG((t + 2) % 3, t + 2);
    bf16x8 af[4], bv[NW];
#pragma unroll
    for (int mf = 0; mf < 4; mf++)
      af[mf] = *(const bf16x8*)&As[bufR][aoff[mf]];
#pragma unroll
    for (int nf = 0; nf < NW; nf++)
      bv[nf] = *(const bf16x8*)&Bs[bufR][boff[nf]];
    LGKM0();
    __builtin_amdgcn_s_setprio(1);
#pragma unroll
    for (int mf = 0; mf < 4; mf++)
#pragma unroll
      for (int nf = 0; nf < NW; nf++)
        acc[mf][nf] = __builtin_amdgcn_mfma_f32_16x16x32_bf16(af[mf], bv[nf],
                                                              acc[mf][nf], 0, 0, 0);
    __builtin_amdgcn_s_setprio(0);
    // counted wait: group t+1 must land before the next tile reads it;
    // group t+2 (the newest loads) stays in flight across the barrier.
    if (t == NT - 2) {
      VMCNT(0);
    } else if (t < NT - 2) {
      if constexpr (NW == 4) { VMCNT(4); } else { VMCNT(3); }
    }
    BAR();
  }

#pragma unroll
  for (int mf = 0; mf < 4; mf++)
#pragma unroll
    for (int nf = 0; nf < NW; nf++)
#pragma unroll
      for (int i = 0; i < 4; i++) {
        const int m = m0 + wm * 64 + mf * 16 + lq * 4 + i;  // C/D row=(lane>>4)*4+i
        const int c = n0 + wn * (NW * 16) + nf * 16 + lr;   //     col=lane&15
        const float v = acc[mf][nf][i];
        if (MODE == 1) {
          Out[(size_t)m * 1024 + c] = v + bias[c];
        } else {
          const int b = m >> 10, n = m & 1023;
          const int which = c >> 10, cc = c & 1023;
          const int hh = cc >> 6, d = cc & 63;
          const size_t qk = ((size_t)((b * 16 + hh) * 1024 + n)) * 64 + d;
          if (which == 0)
            Qb[qk] = (bf16_t)(v * (0.125f * LOG2E));  // fold softmax scale+log2e
          else if (which == 1)
            Kb[qk] = (bf16_t)v;
          else
            Vtb[((size_t)((b * 16 + hh) * 64 + d)) * 1024 + n] = (bf16_t)v;
        }
      }
}

// ------------- flash attention v6: 32x32 MFMA, fully in-register P --------
// (unchanged — correctness proven; kept for clean ablation)
__global__ __launch_bounds__(256) void attn128(const bf16_t* __restrict__ Qb,
                                               const bf16_t* __restrict__ Kb,
                                               const bf16_t* __restrict__ Vtb,
                                               bf16_t* __restrict__ Ob) {
  __shared__ __align__(16) bf16_t Ks[2][64 * 64];
  __shared__ __align__(16) bf16_t Vs[2][64 * 64];
  const int bid = blockIdx.x;
  const int qt = bid >> 7, b = (bid >> 4) & 7, h = bid & 15;
  const bf16_t* Qh = Qb + (size_t)((b * 16 + h) * 1024) * 64;
  const bf16_t* Kh = Kb + (size_t)((b * 16 + h) * 1024) * 64;
  const bf16_t* Vh = Vtb + (size_t)((b * 16 + h) * 64) * 1024;  // [64][1024] = V^T
  const int tid = threadIdx.x, w = tid >> 6, l = tid & 63;
  const int lq31 = l & 31, hi = l >> 5;
  const int q0w = qt * 128 + w * 32;
  const int ksw = lq31 & 7;

  // staging: chunk c = slot*256 + tid; r = c>>3, pos p = tid&7,
  // source chunk = p ^ (r&7)  ((r+32)&7 == r&7 -> slot-invariant)
  const int r0 = tid >> 3, p0 = tid & 7;
  const int ck = (p0 ^ (r0 & 7)) * 8;
  const int ldsS0 = (w * 64) * 8;
  const int ldsS1 = (256 + w * 64) * 8;

#define STGKV(bf_, j_)                                                  \
  do {                                                                  \
    const size_t jb = (size_t)(j_) * 64;                                \
    GL2LDS(&Kh[(jb + r0) * 64 + ck], &Ks[bf_][ldsS0]);                  \
    GL2LDS(&Kh[(jb + r0 + 32) * 64 + ck], &Ks[bf_][ldsS1]);             \
    GL2LDS(&Vh[(size_t)r0 * 1024 + jb + ck], &Vs[bf_][ldsS0]);          \
    GL2LDS(&Vh[(size_t)(r0 + 32) * 1024 + jb + ck], &Vs[bf_][ldsS1]);   \
  } while (0)

  // Q B-frags: B[k=c*16+hi*8+j][n=q=lane&31] = Q[q0w+lq31][c*16+hi*8+j]
  bf16x8 qf[4];
#pragma unroll
  for (int c = 0; c < 4; c++)
    qf[c] = *(const bf16x8*)&Qh[(size_t)(q0w + lq31) * 64 + c * 16 + hi * 8];

  STGKV(0, 0);
  VMCNT(0);
  BAR();

  f32x16 o0 = {}, o1 = {};  // O^T: rows d = db*32 + (reg&3)+8*(reg>>2)+4*hi, col q
  float denom = 0.0f;

  for (int it = 0; it < 16; ++it) {
    const int buf = it & 1;
    if (it < 15) STGKV(buf ^ 1, it + 1);
    // QK^T swapped: s[kb] covers kv rows kb*32..+31, q cols = lane&31
    f32x16 s0 = {}, s1 = {};
    __builtin_amdgcn_s_setprio(1);
#pragma unroll
    for (int c = 0; c < 4; c++) {
      const int col = ((c * 2 + hi) ^ ksw) << 3;
      bf16x8 kf0 = *(const bf16x8*)&Ks[buf][lq31 * 64 + col];
      bf16x8 kf1 = *(const bf16x8*)&Ks[buf][(32 + lq31) * 64 + col];
      s0 = __builtin_amdgcn_mfma_f32_32x32x16_bf16(kf0, qf[c], s0, 0, 0, 0);
      s1 = __builtin_amdgcn_mfma_f32_32x32x16_bf16(kf1, qf[c], s1, 0, 0, 0);
    }
    __builtin_amdgcn_s_setprio(0);
    // exp2 -> bf16 pairs; rowsum of ROUNDED p (matches numerator numerics)
    unsigned wds[16];
    float dl = 0.0f;
#pragma unroll
    for (int j = 0; j < 8; j++) {
      bf16_t e0 = (bf16_t)exp2f(s0[2 * j]), e1 = (bf16_t)exp2f(s0[2 * j + 1]);
      dl += (float)e0 + (float)e1;
      wds[j] = pk2(e0, e1);
    }
#pragma unroll
    for (int j = 0; j < 8; j++) {
      bf16_t e0 = (bf16_t)exp2f(s1[2 * j]), e1 = (bf16_t)exp2f(s1[2 * j + 1]);
      dl += (float)e0 + (float)e1;
      wds[8 + j] = pk2(e0, e1);
    }
    denom += dl + __shfl_xor(dl, 32);
    // build PV B-frags: frag ck needs rows ck*16 + hi*8 + (0..7)
    bf16x8 pf[4];
#pragma unroll
    for (int q2 = 0; q2 < 4; q2++) {
      const int base = (q2 >> 1) * 8 + (q2 & 1) * 4;
      const unsigned a0 = wds[base], a1 = wds[base + 1];
      const unsigned a2 = wds[base + 2], a3 = wds[base + 3];
      const unsigned x0 = __shfl_xor(a0, 32), x1 = __shfl_xor(a1, 32);
      const unsigned x2 = __shfl_xor(a2, 32), x3 = __shfl_xor(a3, 32);
      union { unsigned u[4]; bf16x8 v; } u;
      u.u[0] = hi ? x2 : a0;
      u.u[1] = hi ? x3 : a1;
      u.u[2] = hi ? a2 : x0;
      u.u[3] = hi ? a3 : x1;
      pf[q2] = u.v;
    }
    // PV swapped: o[db] += mfma(V^T-frag, P-frag)
    __builtin_amdgcn_s_setprio(1);
#pragma unroll
    for (int c = 0; c < 4; c++) {
      const int col = ((c * 2 + hi) ^ ksw) << 3;
      bf16x8 vf0 = *(const bf16x8*)&Vs[buf][lq31 * 64 + col];
      bf16x8 vf1 = *(const bf16x8*)&Vs[buf][(32 + lq31) * 64 + col];
      o0 = __builtin_amdgcn_mfma_f32_32x32x16_bf16(vf0, pf[c], o0, 0, 0, 0);
      o1 = __builtin_amdgcn_mfma_f32_32x32x16_bf16(vf1, pf[c], o1, 0, 0, 0);
    }
    __builtin_amdgcn_s_setprio(0);
    VMCNT(0);
    BAR();
  }
  // epilogue: O[q][d], d = db*32 + rg*8 + hi*4 + i, q = lane&31 (lane-local inv)
  const float inv = 1.0f / denom;
  const int grow = b * 1024 + q0w + lq31;
#pragma unroll
  for (int db = 0; db < 2; db++)
#pragma unroll
    for (int rg = 0; rg < 4; rg++) {
      bf16x4 ov;
#pragma unroll
      for (int i = 0; i < 4; i++)
        ov[i] = (bf16_t)((db ? o1[rg * 4 + i] : o0[rg * 4 + i]) * inv);
      *(bf16x4*)&Ob[(size_t)grow * 1024 + h * 64 + db * 32 + rg * 8 + hi * 4] = ov;
    }
}

extern "C" void kernel_launch(void* const* d_in, const int* in_sizes, int n_in,
                              void* d_out, int out_size, void* d_ws, size_t ws_size,
                              hipStream_t stream) {
  const float* x     = (const float*)d_in[0];  // [8,1024,1024] f32
  const float* w_qkv = (const float*)d_in[1];  // [1024,3072] f32
  const float* w_out = (const float*)d_in[2];  // [1024,1024] f32
  const float* b_out = (const float*)d_in[3];  // [1024] f32
  float* out = (float*)d_out;                  // [8,1024,1024] f32

  bf16_t* ws = (bf16_t*)d_ws;
  const size_t SZ = (size_t)8 * 1024 * 1024;  // elems per 16MB buffer
  bf16_t* Qb  = ws;            // [B][H][N][64]  (pre-scaled)
  bf16_t* Kb  = Qb + SZ;       // [B][H][N][64]
  bf16_t* Vtb = Kb + SZ;       // [B][H][64][N]
  bf16_t* Ob  = Vtb + SZ;      // [B*N][H*64]; also aliases Xb (dead after gemm0)
  bf16_t* Wqt = Ob + SZ;       // [3072][1024]
  bf16_t* Wot = Wqt + (size_t)3072 * 1024;  // [1024][1024]
  bf16_t* Xb  = Ob;            // x as bf16 [8192][1024]
  // total ws use: 72 MB

  hipLaunchKernelGGL(convert_f32_bf16, dim3(4096), dim3(256), 0, stream, x, Xb);
  hipLaunchKernelGGL(transpose_f32_bf16, dim3(48, 16), dim3(64, 4), 0, stream,
                     w_qkv, Wqt, 1024, 3072);
  hipLaunchKernelGGL(transpose_f32_bf16, dim3(16, 16), dim3(64, 4), 0, stream,
                     w_out, Wot, 1024, 1024);
  hipLaunchKernelGGL((gemmT<0, 4>), dim3(24, 64), dim3(256), 0, stream,
                     Xb, Wqt, Qb, Kb, Vtb, (const float*)nullptr, (float*)nullptr);
  hipLaunchKernelGGL(attn128, dim3(1024), dim3(256), 0, stream, Qb, Kb, Vtb, Ob);
  hipLaunchKernelGGL((gemmT<1, 2>), dim3(16, 64), dim3(256), 0, stream,
                     Ob, Wot, (bf16_t*)nullptr, (bf16_t*)nullptr, (bf16_t*)nullptr,
                     b_out, out);
}